// Round 1
// baseline (1344.593 us; speedup 1.0000x reference)
//
#include <hip/hip_runtime.h>

// DyGPrompt pretrain: 2-layer temporal graph attention.
// Key restructure vs previous version: the 240000-row edge-feature
// projections (EfK/EfV) are algebraically eliminated:
//   score edge part:  q . (ef @ k_wDE^T) = qtilde_h . ef,
//       qtilde_h = (head-masked k_wDE^T) applied to q   -> 12000-row GEMM
//   output edge part: sum_k w_hk (ef_k @ v_wDE^T) @ out_w^T
//       = agg_h @ M_h^T,  agg_h = sum_k w_hk ef_k (computed in attention),
//       M_h = out_w[:,h-slice] @ v_wDE[h-slice,:]  (device-precomputed).
// Attention reads raw f32 edge rows (same bytes as EfK+EfV bf16) and only
// stages ef in LDS (read twice); NodeK/V / H1K/V rows are consumed once and
// read directly from global. NodeK/V GEMM uses 4 row-blocks/wave to cut
// B-fragment L2 re-reads 4x.

#define NSMP   12000
#define KNB    20
#define EDIM   172
#define HDIM   86
#define NNODES 100000
#define NT_N   11     // ceil(172/16) n-tiles
#define KS_N   6      // ceil(172/32) k-steps
#define NTBL   8
#define TBL_SZ (NT_N * KS_N * 64 * 8)   // elements per pre-swizzled table
#define SKP    176    // padded row stride for sef

typedef unsigned int uint;
typedef unsigned short ushort;
typedef __attribute__((ext_vector_type(8))) short  bf16x8;
typedef __attribute__((ext_vector_type(4))) float  f32x4;

static __device__ __forceinline__ ushort f2bf(float f) {
    uint u = __float_as_uint(f);
    uint r = (u + 0x7fffu + ((u >> 16) & 1u)) >> 16;   // RNE, finite inputs
    return (ushort)r;
}
static __device__ __forceinline__ float bf2f(ushort b) {
    return __uint_as_float(((uint)b) << 16);
}

// Load one wave's A-fragments for a 16-row block. rowp = row base (f32,
// lda=EDIM or caller-offset), quad = lane>>4. Fragment: row = lane&15,
// k = s*32 + quad*8 + j, tail k-step guarded at 172.
static __device__ __forceinline__ void load_afrag(
    const float* __restrict__ rowp, int quad, bf16x8* af)
{
    const float* ap = rowp + quad * 8;
    #pragma unroll
    for (int s = 0; s < KS_N - 1; s++) {
        float4 f0 = *(const float4*)(ap + s * 32);
        float4 f1 = *(const float4*)(ap + s * 32 + 4);
        af[s][0] = f2bf(f0.x); af[s][1] = f2bf(f0.y);
        af[s][2] = f2bf(f0.z); af[s][3] = f2bf(f0.w);
        af[s][4] = f2bf(f1.x); af[s][5] = f2bf(f1.y);
        af[s][6] = f2bf(f1.z); af[s][7] = f2bf(f1.w);
    }
    const int kt = EDIM - 160 - quad * 8;   // 12, 4, -4, -12
    #pragma unroll
    for (int j = 0; j < 8; j++)
        af[KS_N - 1][j] = (j < kt) ? (short)f2bf(ap[160 + j]) : (short)0;
}

// ---------------- time encoding ----------------
__global__ __launch_bounds__(256) void time_enc_kernel(
    const float* __restrict__ ts, const float* __restrict__ tw,
    const float* __restrict__ tb, float* __restrict__ t)
{
    int i = blockIdx.x * 256 + threadIdx.x;
    if (i < NSMP * EDIM) {
        int b = i / EDIM, e = i - b * EDIM;
        t[i] = cosf(ts[b] * tw[e] + tb[e]);
    }
}

// ---------------- winner scatter (last write wins) ----------------
__global__ __launch_bounds__(256) void winner_init_kernel(int* __restrict__ w)
{
    int i = blockIdx.x * 256 + threadIdx.x;
    if (i < NNODES) w[i] = -1;
}
__global__ __launch_bounds__(256) void winner_scatter_kernel(
    const int* __restrict__ nodes, int* __restrict__ w)
{
    int i = blockIdx.x * 256 + threadIdx.x;
    if (i < NSMP) atomicMax(&w[nodes[i]], i);
}
__global__ __launch_bounds__(256) void jmap_kernel(
    const int* __restrict__ nodes, const int* __restrict__ w,
    int* __restrict__ jmap)
{
    int i = blockIdx.x * 256 + threadIdx.x;
    if (i < NSMP) jmap[i] = w[nodes[i]];
}

// ---------------- composite edge-V matrices ----------------
// M_h[i][j] = sum_{d<86} out_w[i][h*86+d] * v_w[h*86+d][172+j]
__global__ __launch_bounds__(256) void mcompute_kernel(
    const float* __restrict__ out_w, const float* __restrict__ v_w,
    float* __restrict__ Mbuf)
{
    int idx = blockIdx.x * 256 + threadIdx.x;
    if (idx >= 2 * EDIM * EDIM) return;
    int h = idx / (EDIM * EDIM);
    int r = idx - h * (EDIM * EDIM);
    int i = r / EDIM, j = r - i * EDIM;
    float s = 0.f;
    for (int d = 0; d < HDIM; d++)
        s += out_w[i * EDIM + h * HDIM + d] *
             v_w[(long)(h * HDIM + d) * (2 * EDIM) + EDIM + j];
    Mbuf[idx] = s;
}

// ---------------- weight pre-swizzle: f32 -> bf16 B-fragments ----
// frag (nt,s,lane) at ((nt*KS_N+s)*64+lane)*8; elem j:
//   W[nt*16 + (lane&15)][s*32 + (lane>>4)*8 + j]  (0 if OOB)
// Tables: 0=q_w 1=out_w 2=k_w[:, :172] 3=v_w[:, :172]
//         4=Wt0: [n][k] = (k< 86) ? k_w[k][172+n] : 0   (head-0 qtilde)
//         5=Wt1: [n][k] = (k>=86) ? k_w[k][172+n] : 0   (head-1 qtilde)
//         6=M0, 7=M1 (composite, from Mbuf)
__global__ __launch_bounds__(256) void preswizzle_kernel(
    const float* __restrict__ q_w, const float* __restrict__ out_w,
    const float* __restrict__ k_w, const float* __restrict__ v_w,
    const float* __restrict__ Mbuf, ushort* __restrict__ BF)
{
    int gid = blockIdx.x * 256 + threadIdx.x;
    int total = NTBL * NT_N * KS_N * 64;
    if (gid >= total) return;
    int tbl  = gid / (NT_N * KS_N * 64);
    int rem  = gid - tbl * (NT_N * KS_N * 64);
    int lane = rem & 63;
    int fs   = rem >> 6;          // nt*KS_N + s
    int s    = fs % KS_N;
    int nt   = fs / KS_N;
    int n    = nt * 16 + (lane & 15);
    int k0   = s * 32 + (lane >> 4) * 8;
    ushort* dst = BF + (size_t)tbl * TBL_SZ + (size_t)(fs * 64 + lane) * 8;
    #pragma unroll
    for (int j = 0; j < 8; j++) {
        int k = k0 + j;
        float val = 0.f;
        if (n < EDIM && k < EDIM) {
            switch (tbl) {
                case 0: val = q_w[(long)n * EDIM + k]; break;
                case 1: val = out_w[(long)n * EDIM + k]; break;
                case 2: val = k_w[(long)n * 2 * EDIM + k]; break;
                case 3: val = v_w[(long)n * 2 * EDIM + k]; break;
                case 4: val = (k <  HDIM) ? k_w[(long)k * 2 * EDIM + EDIM + n] : 0.f; break;
                case 5: val = (k >= HDIM) ? k_w[(long)k * 2 * EDIM + EDIM + n] : 0.f; break;
                case 6: val = Mbuf[(long)n * EDIM + k]; break;
                default: val = Mbuf[(long)EDIM * EDIM + (long)n * EDIM + k]; break;
            }
        }
        dst[j] = f2bf(val);
    }
}

// ---------------- register-fragment MFMA GEMM: C = gather(A) @ W^T -------
// RB = 16-row blocks per wave (amortizes B-fragment loads RB x).
// add1: optional per-element addend for output 1 (row-matched, f32).
template<int RB>
__global__ __launch_bounds__(256) void gemm_rf_kernel(
    const float* __restrict__ A, const int* __restrict__ Aidx, int M,
    const ushort* __restrict__ BF1, const ushort* __restrict__ BF2,
    const float* __restrict__ bias1, const float* __restrict__ bias2,
    const float* __restrict__ add1,
    float* __restrict__ C1f, ushort* __restrict__ C1h,
    float* __restrict__ C2f, ushort* __restrict__ C2h)
{
    const int lane = threadIdx.x & 63;
    const int wave = threadIdx.x >> 6;
    const int col  = lane & 15;
    const int quad = lane >> 4;
    const int m0   = (blockIdx.x * 4 + wave) * (16 * RB);
    if (m0 >= M) return;
    const bool dual = (BF2 != nullptr);

    bf16x8 af[RB][KS_N];
    bool rv[RB];
    #pragma unroll
    for (int rb = 0; rb < RB; rb++) {
        int mr = m0 + rb * 16;
        rv[rb] = (mr < M);
        long arow = rv[rb] ? (long)(mr + col) : 0;
        if (Aidx) arow = (long)Aidx[arow];
        load_afrag(A + arow * EDIM, quad, af[rb]);
    }

    #pragma unroll
    for (int nt = 0; nt < NT_N; nt++) {
        const ushort* bp1 = BF1 + (size_t)(nt * KS_N * 64 + lane) * 8;
        const ushort* bp2 = dual ? BF2 + (size_t)(nt * KS_N * 64 + lane) * 8 : bp1;
        f32x4 acc1[RB], acc2[RB];
        #pragma unroll
        for (int rb = 0; rb < RB; rb++) {
            acc1[rb] = {0.f, 0.f, 0.f, 0.f};
            acc2[rb] = {0.f, 0.f, 0.f, 0.f};
        }
        #pragma unroll
        for (int s = 0; s < KS_N; s++) {
            bf16x8 b1 = *(const bf16x8*)(bp1 + (size_t)s * 64 * 8);
            #pragma unroll
            for (int rb = 0; rb < RB; rb++)
                acc1[rb] = __builtin_amdgcn_mfma_f32_16x16x32_bf16(af[rb][s], b1, acc1[rb], 0, 0, 0);
            if (dual) {
                bf16x8 b2 = *(const bf16x8*)(bp2 + (size_t)s * 64 * 8);
                #pragma unroll
                for (int rb = 0; rb < RB; rb++)
                    acc2[rb] = __builtin_amdgcn_mfma_f32_16x16x32_bf16(af[rb][s], b2, acc2[rb], 0, 0, 0);
            }
        }
        const int n = nt * 16 + col;          // C/D: col = lane&15
        if (n < EDIM) {
            const float bb1 = bias1 ? bias1[n] : 0.f;
            const float bb2 = bias2 ? bias2[n] : 0.f;
            #pragma unroll
            for (int rb = 0; rb < RB; rb++) {
                if (!rv[rb]) continue;
                #pragma unroll
                for (int r = 0; r < 4; r++) {   // C/D: row = quad*4 + r
                    long ci = (long)(m0 + rb * 16 + quad * 4 + r) * EDIM + n;
                    float v1 = acc1[rb][r] + bb1;
                    if (add1) v1 += add1[ci];
                    if (C1f) C1f[ci] = v1; else C1h[ci] = f2bf(v1);
                    if (dual) {
                        float v2 = acc2[rb][r] + bb2;
                        if (C2f) C2f[ci] = v2; else C2h[ci] = f2bf(v2);
                    }
                }
            }
        }
    }
}

// ---------------- output projection: C = A1@out_w^T + agg0@M0^T + agg1@M1^T + bias
__global__ __launch_bounds__(256) void gemm_out3_kernel(
    const float* __restrict__ A1,   // AO, lda = EDIM
    const float* __restrict__ A2,   // AGG, lda = 2*EDIM (two 172-halves)
    int M,
    const ushort* __restrict__ BFo, const ushort* __restrict__ BFm0,
    const ushort* __restrict__ BFm1,
    const float* __restrict__ bias, float* __restrict__ C)
{
    const int lane = threadIdx.x & 63;
    const int wave = threadIdx.x >> 6;
    const int col  = lane & 15;
    const int quad = lane >> 4;
    const int m0   = (blockIdx.x * 4 + wave) * 16;
    if (m0 >= M) return;
    const long arow = m0 + col;

    bf16x8 afo[KS_N], afa[KS_N], afb[KS_N];
    load_afrag(A1 + arow * EDIM, quad, afo);
    load_afrag(A2 + arow * 2 * EDIM, quad, afa);
    load_afrag(A2 + arow * 2 * EDIM + EDIM, quad, afb);

    #pragma unroll
    for (int nt = 0; nt < NT_N; nt++) {
        const ushort* bpo = BFo  + (size_t)(nt * KS_N * 64 + lane) * 8;
        const ushort* bp0 = BFm0 + (size_t)(nt * KS_N * 64 + lane) * 8;
        const ushort* bp1 = BFm1 + (size_t)(nt * KS_N * 64 + lane) * 8;
        f32x4 acc = {0.f, 0.f, 0.f, 0.f};
        #pragma unroll
        for (int s = 0; s < KS_N; s++) {
            bf16x8 bo = *(const bf16x8*)(bpo + (size_t)s * 64 * 8);
            acc = __builtin_amdgcn_mfma_f32_16x16x32_bf16(afo[s], bo, acc, 0, 0, 0);
            bf16x8 b0 = *(const bf16x8*)(bp0 + (size_t)s * 64 * 8);
            acc = __builtin_amdgcn_mfma_f32_16x16x32_bf16(afa[s], b0, acc, 0, 0, 0);
            bf16x8 b1 = *(const bf16x8*)(bp1 + (size_t)s * 64 * 8);
            acc = __builtin_amdgcn_mfma_f32_16x16x32_bf16(afb[s], b1, acc, 0, 0, 0);
        }
        const int n = nt * 16 + col;
        if (n < EDIM) {
            const float bb = bias ? bias[n] : 0.f;
            #pragma unroll
            for (int r = 0; r < 4; r++) {
                long ci = (long)(m0 + quad * 4 + r) * EDIM + n;
                C[ci] = acc[r] + bb;
            }
        }
    }
}

// ---------------- per-sample attention ----------------
// Inputs per sample b: Q (q incl. t-part & bq), QT0/QT1 (per-head qtilde),
// TV (t@v_wE^T + bv). K/V node rows read directly from NodeK/V (bf16) or
// H1K/H1V (f32, winner-scattered). Raw f32 edge rows staged in LDS (used by
// scores and by the agg reduction). Outputs: AO (node-V + TV part, 172) and
// AGG (per-head weighted edge-feature sums, 344).
__global__ __launch_bounds__(256) void attn_kernel(
    const int* __restrict__ neighbors, const int* __restrict__ eidx,
    const float* __restrict__ Q, const float* __restrict__ QT0,
    const float* __restrict__ QT1, const float* __restrict__ TV,
    const float* __restrict__ edgef,
    const int* __restrict__ winner,
    const ushort* __restrict__ NodeK, const ushort* __restrict__ NodeV,
    const float* __restrict__ H1K, const float* __restrict__ H1V,
    float* __restrict__ AO, float* __restrict__ AGG)
{
    const int b = blockIdx.x;
    const int t = threadIdx.x;
    __shared__ float sq[SKP], sq0[SKP], sq1[SKP];
    __shared__ float sef[KNB * SKP];
    __shared__ float sw[2][KNB];
    __shared__ int   snb[KNB], sei[KNB], swin[KNB], spad[KNB];

    if (t < KNB) {
        int nb = neighbors[b * KNB + t];
        snb[t]  = nb;
        spad[t] = (nb == 0) ? 1 : 0;
        sei[t]  = eidx[b * KNB + t];
    }
    if (t < EDIM) {
        sq[t]  = Q[(long)b * EDIM + t];
        sq0[t] = QT0[(long)b * EDIM + t];
        sq1[t] = QT1[(long)b * EDIM + t];
    }
    __syncthreads();

    if (t < KNB) swin[t] = winner ? winner[snb[t]] : -1;
    if (t == 0) {   // all-padded row: unmask neighbor 0
        int c = 0;
        for (int k = 0; k < KNB; k++) c += spad[k];
        if (c == KNB) spad[0] = 0;
    }
    // stage raw edge rows: 20 x 43 chunks of 4 f32
    for (int task = t; task < KNB * 43; task += 256) {
        int kk = task / 43, c = task - kk * 43, e = c * 4;
        float4 ef4 = *(const float4*)(edgef + (long)sei[kk] * EDIM + e);
        float* p = &sef[kk * SKP + e];
        p[0] = ef4.x; p[1] = ef4.y; p[2] = ef4.z; p[3] = ef4.w;
    }
    __syncthreads();

    // scores: (kk,h,part): node dot (22 of 86) + edge dot (43 of 172)
    if (t < 2 * KNB * 4) {
        int kk = t >> 3, h = (t >> 2) & 1, part = t & 3;
        int d0 = part * 22, d1 = d0 + 22; if (d1 > HDIM) d1 = HDIM;
        const float* qp = &sq[h * HDIM];
        float s = 0.f;
        int w = swin[kk];
        if (w >= 0) {
            const float* kp = H1K + (long)w * EDIM + h * HDIM;
            for (int d = d0; d < d1; d++) s += qp[d] * kp[d];
        } else {
            const ushort* kp = NodeK + (long)snb[kk] * EDIM + h * HDIM;
            for (int d = d0; d < d1; d++) s += qp[d] * bf2f(kp[d]);
        }
        const float* qt = h ? sq1 : sq0;
        const float* ep = &sef[kk * SKP];
        int i0 = part * 43;
        for (int i = i0; i < i0 + 43; i++) s += qt[i] * ep[i];
        s += __shfl_xor(s, 1, 64);
        s += __shfl_xor(s, 2, 64);
        if (part == 0)
            sw[h][kk] = spad[kk] ? -1e9f : (s * 0.10783277320343841f);  // 1/sqrt(86)
    }
    __syncthreads();
    if (t < 2) {
        float mx = -1e30f;
        for (int kk = 0; kk < KNB; kk++) mx = fmaxf(mx, sw[t][kk]);
        float sum = 0.f, ex[KNB];
        for (int kk = 0; kk < KNB; kk++) { ex[kk] = expf(sw[t][kk] - mx); sum += ex[kk]; }
        float inv = 1.f / sum;
        for (int kk = 0; kk < KNB; kk++) sw[t][kk] = ex[kk] * inv;
    }
    __syncthreads();
    if (t < EDIM) {
        int h = t / HDIM;
        float acc = 0.f, a0 = 0.f, a1 = 0.f;
        for (int kk = 0; kk < KNB; kk++) {
            float w0 = sw[0][kk], w1 = sw[1][kk];
            int w = swin[kk];
            float vv = (w >= 0) ? H1V[(long)w * EDIM + t]
                                : bf2f(NodeV[(long)snb[kk] * EDIM + t]);
            acc += (h ? w1 : w0) * vv;
            float ev = sef[kk * SKP + t];
            a0 += w0 * ev;
            a1 += w1 * ev;
        }
        AO[(long)b * EDIM + t] = acc + TV[(long)b * EDIM + t];
        AGG[(long)b * 2 * EDIM + t] = a0;
        AGG[(long)b * 2 * EDIM + EDIM + t] = a1;
    }
}

extern "C" void kernel_launch(void* const* d_in, const int* in_sizes, int n_in,
                              void* d_out, int out_size, void* d_ws, size_t ws_size,
                              hipStream_t stream)
{
    const int*   nodes   = (const int*)d_in[0];
    const float* ts      = (const float*)d_in[1];
    const int*   neigh   = (const int*)d_in[2];
    const int*   edgeidx = (const int*)d_in[3];
    const float* nodef   = (const float*)d_in[4];
    const float* edgef   = (const float*)d_in[5];
    const float* time_w  = (const float*)d_in[6];
    const float* time_b  = (const float*)d_in[7];
    const float* q_w     = (const float*)d_in[8];
    const float* k_w     = (const float*)d_in[9];
    const float* v_w     = (const float*)d_in[10];
    const float* bq      = (const float*)d_in[11];
    const float* bv      = (const float*)d_in[13];
    const float* out_w   = (const float*)d_in[14];
    const float* out_b   = (const float*)d_in[15];
    float* out = (float*)d_out;

    char* wsp = (char*)d_ws;
    size_t off = 0;
    auto alloc = [&](size_t bytes) -> void* {
        void* p = wsp + off;
        off += (bytes + 255) & ~(size_t)255;
        return p;
    };
    const size_t SE = (size_t)NSMP * EDIM;
    float* t_enc = (float*)alloc(SE * 4);
    float* TQ    = (float*)alloc(SE * 4);
    float* TV    = (float*)alloc(SE * 4);
    float* Qb    = (float*)alloc(SE * 4);
    float* QT0   = (float*)alloc(SE * 4);
    float* QT1   = (float*)alloc(SE * 4);
    float* AO    = (float*)alloc(SE * 4);
    float* H1    = (float*)alloc(SE * 4);
    float* H1K   = (float*)alloc(SE * 4);
    float* H1V   = (float*)alloc(SE * 4);
    float* AGG   = (float*)alloc((size_t)NSMP * 2 * EDIM * 4);
    float* Mbuf  = (float*)alloc((size_t)2 * EDIM * EDIM * 4);
    int*   winner = (int*)alloc((size_t)NNODES * 4);
    int*   jmap   = (int*)alloc((size_t)NSMP * 4);
    ushort* NodeK = (ushort*)alloc((size_t)NNODES * EDIM * 2);
    ushort* NodeV = (ushort*)alloc((size_t)NNODES * EDIM * 2);
    ushort* BF    = (ushort*)alloc((size_t)NTBL * TBL_SZ * 2);
    if (off > ws_size) return;

    const ushort* BFq   = BF + 0 * TBL_SZ;
    const ushort* BFout = BF + 1 * TBL_SZ;
    const ushort* BFkE  = BF + 2 * TBL_SZ;
    const ushort* BFvE  = BF + 3 * TBL_SZ;
    const ushort* BFW0  = BF + 4 * TBL_SZ;
    const ushort* BFW1  = BF + 5 * TBL_SZ;
    const ushort* BFM0  = BF + 6 * TBL_SZ;
    const ushort* BFM1  = BF + 7 * TBL_SZ;

    dim3 blk(256);
    const int gS = (NSMP + 63) / 64;            // 188 (M=12000, %16==0)

    winner_init_kernel<<<(NNODES + 255) / 256, blk, 0, stream>>>(winner);
    winner_scatter_kernel<<<(NSMP + 255) / 256, blk, 0, stream>>>(nodes, winner);
    mcompute_kernel<<<(2 * EDIM * EDIM + 255) / 256, blk, 0, stream>>>(out_w, v_w, Mbuf);
    preswizzle_kernel<<<(NTBL * NT_N * KS_N * 64 + 255) / 256, blk, 0, stream>>>(
        q_w, out_w, k_w, v_w, Mbuf, BF);
    time_enc_kernel<<<(NSMP * EDIM + 255) / 256, blk, 0, stream>>>(ts, time_w, time_b, t_enc);

    // TQ = t@q_w.T + bq ; TV = t@v_wE.T + bv
    gemm_rf_kernel<1><<<gS, blk, 0, stream>>>(t_enc, nullptr, NSMP,
        BFq, BFvE, bq, bv, nullptr, TQ, nullptr, TV, nullptr);
    // NodeK/V (bf16 out), 64 rows/wave
    gemm_rf_kernel<4><<<(NNODES + 255) / 256, blk, 0, stream>>>(nodef, nullptr, NNODES,
        BFkE, BFvE, nullptr, nullptr, nullptr, nullptr, NodeK, nullptr, NodeV);
    // Q1 = nf[nodes]@q_w.T + TQ  (TQ carries bq)
    gemm_rf_kernel<1><<<gS, blk, 0, stream>>>(nodef, nodes, NSMP,
        BFq, nullptr, nullptr, nullptr, TQ, Qb, nullptr, nullptr, nullptr);
    // per-head qtilde: QT_h = Q1 @ Wt_h^T
    gemm_rf_kernel<1><<<gS, blk, 0, stream>>>(Qb, nullptr, NSMP,
        BFW0, BFW1, nullptr, nullptr, nullptr, QT0, nullptr, QT1, nullptr);

    // layer 1 attention -> AO, AGG
    attn_kernel<<<NSMP, blk, 0, stream>>>(neigh, edgeidx, Qb, QT0, QT1, TV,
        edgef, nullptr, NodeK, NodeV, nullptr, nullptr, AO, AGG);
    // h1 = AO@out_w.T + agg0@M0^T + agg1@M1^T + out_b
    gemm_out3_kernel<<<gS, blk, 0, stream>>>(AO, AGG, NSMP,
        BFout, BFM0, BFM1, out_b, H1);

    jmap_kernel<<<(NSMP + 255) / 256, blk, 0, stream>>>(nodes, winner, jmap);
    // layer-2 node projections of h1
    gemm_rf_kernel<1><<<gS, blk, 0, stream>>>(H1, nullptr, NSMP,
        BFkE, BFvE, nullptr, nullptr, nullptr, H1K, nullptr, H1V, nullptr);
    // Q2 = h1[winner[nodes]]@q_w.T + TQ
    gemm_rf_kernel<1><<<gS, blk, 0, stream>>>(H1, jmap, NSMP,
        BFq, nullptr, nullptr, nullptr, TQ, Qb, nullptr, nullptr, nullptr);
    gemm_rf_kernel<1><<<gS, blk, 0, stream>>>(Qb, nullptr, NSMP,
        BFW0, BFW1, nullptr, nullptr, nullptr, QT0, nullptr, QT1, nullptr);

    // layer 2 attention
    attn_kernel<<<NSMP, blk, 0, stream>>>(neigh, edgeidx, Qb, QT0, QT1, TV,
        edgef, winner, NodeK, NodeV, H1K, H1V, AO, AGG);
    // final -> d_out
    gemm_out3_kernel<<<gS, blk, 0, stream>>>(AO, AGG, NSMP,
        BFout, BFM0, BFM1, out_b, out);
}